// Round 6
// baseline (216.635 us; speedup 1.0000x reference)
//
#include <hip/hip_runtime.h>
#include <hip/hip_bf16.h>
#include <math.h>

namespace {

constexpr int BSZ = 2, LEN = 2048, DIM = 2048, NST = 16, RNK = 128;
constexpr int NC = 64, CHUNK = LEN / NC;          // 64 chunks of 32
constexpr int KS = 3 * RNK;                       // split-K = 384
constexpr float LOG2E = 1.4426950408889634f;
constexpr float LN2 = 0.6931471805599453f;

using bf16x8 = __attribute__((ext_vector_type(8))) short;
using f32x4  = __attribute__((ext_vector_type(4))) float;

__device__ __forceinline__ float fast_exp2(float x) {
#if __has_builtin(__builtin_amdgcn_exp2f)
  return __builtin_amdgcn_exp2f(x);
#else
  return exp2f(x);
#endif
}

__device__ __forceinline__ unsigned short bf16_rne(float x) {
  __hip_bfloat16 h = __float2bfloat16(x);
  return *(unsigned short*)&h;
}
__device__ __forceinline__ float bf16_tof(unsigned short u) {
  __hip_bfloat16 h = *(__hip_bfloat16*)&u;
  return __bfloat162float(h);
}

// ---------- Kernel 0: split f32 -> bf16 hi/lo, padded K=384 layouts ----------
// Ad: [B*L=4096][384] = [hi | lo | hi];  Bd: [D=2048][384] = [hi | hi | lo]
__global__ __launch_bounds__(256)
void split_bf16(const float* __restrict__ delta, const float* __restrict__ W,
                unsigned short* __restrict__ Ad, unsigned short* __restrict__ Bd) {
  int t = blockIdx.x * 256 + threadIdx.x;
  const int NA = BSZ * LEN * RNK;                 // 524288
  if (t < NA) {
    int row = t >> 7, k = t & (RNK - 1);
    float x = delta[t];
    unsigned short hi = bf16_rne(x);
    unsigned short lo = bf16_rne(x - bf16_tof(hi));
    unsigned short* p = Ad + (size_t)row * KS;
    p[k] = hi; p[RNK + k] = lo; p[2 * RNK + k] = hi;
  } else {
    t -= NA;                                      // 262144 W elements
    int row = t >> 7, k = t & (RNK - 1);
    float x = W[t];
    unsigned short hi = bf16_rne(x);
    unsigned short lo = bf16_rne(x - bf16_tof(hi));
    unsigned short* p = Bd + (size_t)row * KS;
    p[k] = hi; p[RNK + k] = hi; p[2 * RNK + k] = lo;
  }
}

// ---------- shared device fn: dt tile [32 l][256 d] via MFMA -> LDS ----------
__device__ __forceinline__ void compute_dt_tile(
    const unsigned short* __restrict__ Ad, const unsigned short* __restrict__ Bd,
    const float* __restrict__ bias, int b, int l0, int dgrp,
    float (*dt_tile)[256]) {
  const int lane = threadIdx.x & 63, w = threadIdx.x >> 6;
  const int r = lane & 15, kg = lane >> 4;
  const unsigned short* arow = Ad + (size_t)(b * LEN + l0 + r) * KS + kg * 8;
  const unsigned short* brow = Bd + (size_t)(dgrp * 256 + w * 64 + r) * KS + kg * 8;

  f32x4 acc[2][4] = {};
#pragma unroll
  for (int ks = 0; ks < KS / 32; ++ks) {          // 12 k-steps of 32
    bf16x8 af[2], bfr[4];
    af[0] = *(const bf16x8*)(arow + ks * 32);
    af[1] = *(const bf16x8*)(arow + (size_t)16 * KS + ks * 32);
#pragma unroll
    for (int n = 0; n < 4; ++n)
      bfr[n] = *(const bf16x8*)(brow + (size_t)n * 16 * KS + ks * 32);
#pragma unroll
    for (int m = 0; m < 2; ++m)
#pragma unroll
      for (int n = 0; n < 4; ++n)
        acc[m][n] = __builtin_amdgcn_mfma_f32_16x16x32_bf16(af[m], bfr[n], acc[m][n], 0, 0, 0);
  }
#pragma unroll
  for (int n = 0; n < 4; ++n) {
    const int dl = w * 64 + n * 16 + r;
    const float bs = bias[dgrp * 256 + dl];
#pragma unroll
    for (int m = 0; m < 2; ++m) {
      const int row0 = m * 16 + kg * 4;
#pragma unroll
      for (int j = 0; j < 4; ++j) {
        float z = acc[m][n][j] + bs;
        float sp = fmaxf(z, 0.f) + LN2 * __log2f(1.0f + fast_exp2(-fabsf(z) * LOG2E));
        dt_tile[row0 + j][dl] = sp;
      }
    }
  }
}

// ---------- Kernel 1: fused dt + local scan -> S (local state), sdt ----------
__global__ __launch_bounds__(256, 4)
void scan1_fused(const unsigned short* __restrict__ Ad, const unsigned short* __restrict__ Bd,
                 const float* __restrict__ bias, const float* __restrict__ x,
                 const float* __restrict__ Bin, const float* __restrict__ Alog,
                 float* __restrict__ Sout, float* __restrict__ sdtout) {
  __shared__ float dt_tile[CHUNK][256];           // 32 KiB
  __shared__ float4 Bl[CHUNK * NST / 4];          // 2 KiB
  const int tid = threadIdx.x;
  const int bz = blockIdx.x;
  const int dgrp = bz & 7;
  const int c = (bz >> 3) & (NC - 1);
  const int b = bz >> 9;
  const int d = dgrp * 256 + tid;
  const int l0 = c * CHUNK;

  if (tid < CHUNK * NST / 4)
    Bl[tid] = ((const float4*)(Bin + ((size_t)b * LEN + l0) * NST))[tid];

  // Issue ALL x loads up front (T14: issue-early). Latency hides under MFMA.
  const float* xp = x + ((size_t)b * LEN + l0) * DIM + d;
  float xr[CHUNK];
#pragma unroll
  for (int i = 0; i < CHUNK; ++i) xr[i] = xp[(size_t)i * DIM];

  compute_dt_tile(Ad, Bd, bias, b, l0, dgrp, dt_tile);

  float A2[NST];
  {
    const float4* ap = (const float4*)(Alog + (size_t)d * NST);
#pragma unroll
    for (int q = 0; q < 4; ++q) {
      float4 v = ap[q];
      A2[q * 4 + 0] = -expf(v.x) * LOG2E;
      A2[q * 4 + 1] = -expf(v.y) * LOG2E;
      A2[q * 4 + 2] = -expf(v.z) * LOG2E;
      A2[q * 4 + 3] = -expf(v.w) * LOG2E;
    }
  }
  __syncthreads();

  float h[NST];
#pragma unroll
  for (int n = 0; n < NST; ++n) h[n] = 0.f;
  float sdt = 0.f;

#pragma unroll
  for (int i = 0; i < CHUNK; ++i) {
    float dt = dt_tile[i][tid];
    float dtx = dt * xr[i];
    sdt += dt;
#pragma unroll
    for (int q = 0; q < 4; ++q) {
      float4 Bv = Bl[i * 4 + q];
      float e0 = fast_exp2(dt * A2[q * 4 + 0]);
      float e1 = fast_exp2(dt * A2[q * 4 + 1]);
      float e2 = fast_exp2(dt * A2[q * 4 + 2]);
      float e3 = fast_exp2(dt * A2[q * 4 + 3]);
      h[q * 4 + 0] = fmaf(e0, h[q * 4 + 0], dtx * Bv.x);
      h[q * 4 + 1] = fmaf(e1, h[q * 4 + 1], dtx * Bv.y);
      h[q * 4 + 2] = fmaf(e2, h[q * 4 + 2], dtx * Bv.z);
      h[q * 4 + 3] = fmaf(e3, h[q * 4 + 3], dtx * Bv.w);
    }
  }

  const size_t obase = ((size_t)(b * NC + c) * DIM + d) * NST;
#pragma unroll
  for (int q = 0; q < 4; ++q) {
    float4 sv = {h[q * 4 + 0], h[q * 4 + 1], h[q * 4 + 2], h[q * 4 + 3]};
    *(float4*)&Sout[obase + q * 4] = sv;
  }
  sdtout[(size_t)(b * NC + c) * DIM + d] = sdt;
}

// ---------- Kernel 2: sequential combine; h_init written in-place into S ----------
// Prefetch ALL 64 chunk summaries into registers, then run the fma chain.
__global__ __launch_bounds__(256)
void chunk_combine(const float* __restrict__ sdt, float* __restrict__ S,
                   const float* __restrict__ Alog) {
  const int t = blockIdx.x * 256 + threadIdx.x;   // B*D*N = 65536 threads
  const int n = t & (NST - 1);
  const int d = (t >> 4) & (DIM - 1);
  const int b = t >> 15;
  const float a2 = -expf(Alog[(size_t)d * NST + n]) * LOG2E;

  float sv[NC], sdv[NC];
#pragma unroll
  for (int c = 0; c < NC; ++c) {
    const size_t idx = ((size_t)(b * NC + c) * DIM + d) * NST + n;
    sv[c] = S[idx];
    sdv[c] = sdt[(size_t)(b * NC + c) * DIM + d];
  }
  float cur = 0.f;
#pragma unroll
  for (int c = 0; c < NC; ++c) {
    const size_t idx = ((size_t)(b * NC + c) * DIM + d) * NST + n;
    S[idx] = cur;                                  // h_init for chunk c
    cur = fmaf(fast_exp2(sdv[c] * a2), cur, sv[c]);
  }
}

// ---------- Kernel 3: fused dt + re-scan from h_init, emit y + x*D ----------
__global__ __launch_bounds__(256, 4)
void scan2_fused(const unsigned short* __restrict__ Ad, const unsigned short* __restrict__ Bd,
                 const float* __restrict__ bias, const float* __restrict__ x,
                 const float* __restrict__ Bin, const float* __restrict__ Cin,
                 const float* __restrict__ Alog, const float* __restrict__ Dpar,
                 const float* __restrict__ Hin, float* __restrict__ out) {
  __shared__ float dt_tile[CHUNK][256];           // 32 KiB
  __shared__ float4 Bl[CHUNK * NST / 4];
  __shared__ float4 Cl[CHUNK * NST / 4];
  const int tid = threadIdx.x;
  const int bz = blockIdx.x;
  const int dgrp = bz & 7;
  const int c = (bz >> 3) & (NC - 1);
  const int b = bz >> 9;
  const int d = dgrp * 256 + tid;
  const int l0 = c * CHUNK;

  if (tid < CHUNK * NST / 4)
    Bl[tid] = ((const float4*)(Bin + ((size_t)b * LEN + l0) * NST))[tid];
  else if (tid < CHUNK * NST / 2)
    Cl[tid - CHUNK * NST / 4] = ((const float4*)(Cin + ((size_t)b * LEN + l0) * NST))[tid - CHUNK * NST / 4];

  // Issue ALL x loads up front; latency hides under MFMA.
  const float* xp = x + ((size_t)b * LEN + l0) * DIM + d;
  float xr[CHUNK];
#pragma unroll
  for (int i = 0; i < CHUNK; ++i) xr[i] = xp[(size_t)i * DIM];

  compute_dt_tile(Ad, Bd, bias, b, l0, dgrp, dt_tile);

  // h_init prefetch: overlaps A2 transcendentals + barrier.
  const size_t obase = ((size_t)(b * NC + c) * DIM + d) * NST;
  float h[NST];
#pragma unroll
  for (int q = 0; q < 4; ++q) {
    float4 hv = *(const float4*)&Hin[obase + q * 4];
    h[q * 4 + 0] = hv.x; h[q * 4 + 1] = hv.y; h[q * 4 + 2] = hv.z; h[q * 4 + 3] = hv.w;
  }

  float A2[NST];
  {
    const float4* ap = (const float4*)(Alog + (size_t)d * NST);
#pragma unroll
    for (int q = 0; q < 4; ++q) {
      float4 v = ap[q];
      A2[q * 4 + 0] = -expf(v.x) * LOG2E;
      A2[q * 4 + 1] = -expf(v.y) * LOG2E;
      A2[q * 4 + 2] = -expf(v.z) * LOG2E;
      A2[q * 4 + 3] = -expf(v.w) * LOG2E;
    }
  }
  const float dpar = Dpar[d];
  __syncthreads();

  float* op = out + ((size_t)b * LEN + l0) * DIM + d;

#pragma unroll
  for (int i = 0; i < CHUNK; ++i) {
    float dt = dt_tile[i][tid];
    float xc = xr[i];
    float dtx = dt * xc;
    float y0 = 0.f, y1 = 0.f, y2 = 0.f, y3 = 0.f;
#pragma unroll
    for (int q = 0; q < 4; ++q) {
      float4 Bv = Bl[i * 4 + q];
      float4 Cv = Cl[i * 4 + q];
      float e0 = fast_exp2(dt * A2[q * 4 + 0]);
      float e1 = fast_exp2(dt * A2[q * 4 + 1]);
      float e2 = fast_exp2(dt * A2[q * 4 + 2]);
      float e3 = fast_exp2(dt * A2[q * 4 + 3]);
      float hh0 = fmaf(e0, h[q * 4 + 0], dtx * Bv.x);
      float hh1 = fmaf(e1, h[q * 4 + 1], dtx * Bv.y);
      float hh2 = fmaf(e2, h[q * 4 + 2], dtx * Bv.z);
      float hh3 = fmaf(e3, h[q * 4 + 3], dtx * Bv.w);
      h[q * 4 + 0] = hh0; h[q * 4 + 1] = hh1; h[q * 4 + 2] = hh2; h[q * 4 + 3] = hh3;
      float yq = hh0 * Cv.x;
      yq = fmaf(hh1, Cv.y, yq);
      yq = fmaf(hh2, Cv.z, yq);
      yq = fmaf(hh3, Cv.w, yq);
      if (q == 0) y0 = yq; else if (q == 1) y1 = yq; else if (q == 2) y2 = yq; else y3 = yq;
    }
    op[(size_t)i * DIM] = fmaf(xc, dpar, (y0 + y1) + (y2 + y3));
  }
}

}  // namespace

extern "C" void kernel_launch(void* const* d_in, const int* in_sizes, int n_in,
                              void* d_out, int out_size, void* d_ws, size_t ws_size,
                              hipStream_t stream) {
  const float* x     = (const float*)d_in[0];
  const float* delta = (const float*)d_in[1];
  const float* Bin   = (const float*)d_in[2];
  const float* Cin   = (const float*)d_in[3];
  const float* Wdt   = (const float*)d_in[4];
  const float* bdt   = (const float*)d_in[5];
  const float* Alog  = (const float*)d_in[6];
  const float* Dpar  = (const float*)d_in[7];
  float* out = (float*)d_out;

  char* ws = (char*)d_ws;
  size_t off = 0;
  float* S   = (float*)(ws + off); off += (size_t)BSZ * NC * DIM * NST * 4;     // 16 MiB
  float* sdt = (float*)(ws + off); off += (size_t)BSZ * NC * DIM * 4;           // 1 MiB
  unsigned short* Ad = (unsigned short*)(ws + off); off += (size_t)BSZ * LEN * KS * 2;  // 3 MiB
  unsigned short* Bd = (unsigned short*)(ws + off); off += (size_t)DIM * KS * 2;        // 1.5 MiB

  split_bf16<<<(BSZ * LEN * RNK + DIM * RNK) / 256, 256, 0, stream>>>(delta, Wdt, Ad, Bd);
  scan1_fused<<<BSZ * NC * (DIM / 256), 256, 0, stream>>>(Ad, Bd, bdt, x, Bin, Alog, S, sdt);
  chunk_combine<<<BSZ * DIM * NST / 256, 256, 0, stream>>>(sdt, S, Alog);
  scan2_fused<<<BSZ * NC * (DIM / 256), 256, 0, stream>>>(Ad, Bd, bdt, x, Bin, Cin, Alog, Dpar, S, out);
}

// Round 7
// 211.479 us; speedup vs baseline: 1.0244x; 1.0244x over previous
//
#include <hip/hip_runtime.h>
#include <hip/hip_bf16.h>
#include <math.h>

namespace {

constexpr int BSZ = 2, LEN = 2048, DIM = 2048, NST = 16, RNK = 128;
constexpr int NC = 64, CHUNK = LEN / NC;          // 64 chunks of 32
constexpr int KS = 3 * RNK;                       // split-K = 384
constexpr float LOG2E = 1.4426950408889634f;
constexpr float LN2 = 0.6931471805599453f;

using bf16x8 = __attribute__((ext_vector_type(8))) short;
using f32x4  = __attribute__((ext_vector_type(4))) float;

__device__ __forceinline__ float fast_exp2(float x) {
#if __has_builtin(__builtin_amdgcn_exp2f)
  return __builtin_amdgcn_exp2f(x);
#else
  return exp2f(x);
#endif
}

__device__ __forceinline__ unsigned short bf16_rne(float x) {
  __hip_bfloat16 h = __float2bfloat16(x);
  return *(unsigned short*)&h;
}
__device__ __forceinline__ float bf16_tof(unsigned short u) {
  __hip_bfloat16 h = *(__hip_bfloat16*)&u;
  return __bfloat162float(h);
}

// ---------- Kernel 0: split f32 -> bf16 hi/lo, padded K=384 layouts ----------
// Ad: [B*L=4096][384] = [hi | lo | hi];  Bd: [D=2048][384] = [hi | hi | lo]
__global__ __launch_bounds__(256)
void split_bf16(const float* __restrict__ delta, const float* __restrict__ W,
                unsigned short* __restrict__ Ad, unsigned short* __restrict__ Bd) {
  int t = blockIdx.x * 256 + threadIdx.x;
  const int NA = BSZ * LEN * RNK;                 // 524288
  if (t < NA) {
    int row = t >> 7, k = t & (RNK - 1);
    float x = delta[t];
    unsigned short hi = bf16_rne(x);
    unsigned short lo = bf16_rne(x - bf16_tof(hi));
    unsigned short* p = Ad + (size_t)row * KS;
    p[k] = hi; p[RNK + k] = lo; p[2 * RNK + k] = hi;
  } else {
    t -= NA;                                      // 262144 W elements
    int row = t >> 7, k = t & (RNK - 1);
    float x = W[t];
    unsigned short hi = bf16_rne(x);
    unsigned short lo = bf16_rne(x - bf16_tof(hi));
    unsigned short* p = Bd + (size_t)row * KS;
    p[k] = hi; p[RNK + k] = hi; p[2 * RNK + k] = lo;
  }
}

// ---------- shared device fn: dt tile [32 l][256 d] via MFMA -> LDS ----------
__device__ __forceinline__ void compute_dt_tile(
    const unsigned short* __restrict__ Ad, const unsigned short* __restrict__ Bd,
    const float* __restrict__ bias, int b, int l0, int dgrp,
    float (*dt_tile)[256]) {
  const int lane = threadIdx.x & 63, w = threadIdx.x >> 6;
  const int r = lane & 15, kg = lane >> 4;
  const unsigned short* arow = Ad + (size_t)(b * LEN + l0 + r) * KS + kg * 8;
  const unsigned short* brow = Bd + (size_t)(dgrp * 256 + w * 64 + r) * KS + kg * 8;

  f32x4 acc[2][4] = {};
#pragma unroll
  for (int ks = 0; ks < KS / 32; ++ks) {          // 12 k-steps of 32
    bf16x8 af[2], bfr[4];
    af[0] = *(const bf16x8*)(arow + ks * 32);
    af[1] = *(const bf16x8*)(arow + (size_t)16 * KS + ks * 32);
#pragma unroll
    for (int n = 0; n < 4; ++n)
      bfr[n] = *(const bf16x8*)(brow + (size_t)n * 16 * KS + ks * 32);
#pragma unroll
    for (int m = 0; m < 2; ++m)
#pragma unroll
      for (int n = 0; n < 4; ++n)
        acc[m][n] = __builtin_amdgcn_mfma_f32_16x16x32_bf16(af[m], bfr[n], acc[m][n], 0, 0, 0);
  }
#pragma unroll
  for (int n = 0; n < 4; ++n) {
    const int dl = w * 64 + n * 16 + r;
    const float bs = bias[dgrp * 256 + dl];
#pragma unroll
    for (int m = 0; m < 2; ++m) {
      const int row0 = m * 16 + kg * 4;
#pragma unroll
      for (int j = 0; j < 4; ++j) {
        float z = acc[m][n][j] + bs;
        float sp = fmaxf(z, 0.f) + LN2 * __log2f(1.0f + fast_exp2(-fabsf(z) * LOG2E));
        dt_tile[row0 + j][dl] = sp;
      }
    }
  }
}

// ---------- Kernel 1: fused dt + local scan -> S (local state), sdt ----------
__global__ __launch_bounds__(256)
void scan1_fused(const unsigned short* __restrict__ Ad, const unsigned short* __restrict__ Bd,
                 const float* __restrict__ bias, const float* __restrict__ x,
                 const float* __restrict__ Bin, const float* __restrict__ Alog,
                 float* __restrict__ Sout, float* __restrict__ sdtout) {
  __shared__ float dt_tile[CHUNK][256];           // 32 KiB
  __shared__ float4 Bl[CHUNK * NST / 4];          // 2 KiB
  const int tid = threadIdx.x;
  const int bz = blockIdx.x;
  const int dgrp = bz & 7;
  const int c = (bz >> 3) & (NC - 1);
  const int b = bz >> 9;
  const int d = dgrp * 256 + tid;
  const int l0 = c * CHUNK;

  if (tid < CHUNK * NST / 4)
    Bl[tid] = ((const float4*)(Bin + ((size_t)b * LEN + l0) * NST))[tid];

  // 8-deep ring prefetch of x; first 8 issued before MFMA so latency hides.
  const float* xp = x + ((size_t)b * LEN + l0) * DIM + d;
  float xr[8];
#pragma unroll
  for (int i = 0; i < 8; ++i) xr[i] = xp[(size_t)i * DIM];

  compute_dt_tile(Ad, Bd, bias, b, l0, dgrp, dt_tile);

  float A2[NST];
  {
    const float4* ap = (const float4*)(Alog + (size_t)d * NST);
#pragma unroll
    for (int q = 0; q < 4; ++q) {
      float4 v = ap[q];
      A2[q * 4 + 0] = -expf(v.x) * LOG2E;
      A2[q * 4 + 1] = -expf(v.y) * LOG2E;
      A2[q * 4 + 2] = -expf(v.z) * LOG2E;
      A2[q * 4 + 3] = -expf(v.w) * LOG2E;
    }
  }
  __syncthreads();

  float h[NST];
#pragma unroll
  for (int n = 0; n < NST; ++n) h[n] = 0.f;
  float sdt = 0.f;

#pragma unroll
  for (int i = 0; i < CHUNK; ++i) {
    float xc = xr[i & 7];
    if (i + 8 < CHUNK) xr[i & 7] = xp[(size_t)(i + 8) * DIM];
    float dt = dt_tile[i][tid];
    float dtx = dt * xc;
    sdt += dt;
#pragma unroll
    for (int q = 0; q < 4; ++q) {
      float4 Bv = Bl[i * 4 + q];
      float e0 = fast_exp2(dt * A2[q * 4 + 0]);
      float e1 = fast_exp2(dt * A2[q * 4 + 1]);
      float e2 = fast_exp2(dt * A2[q * 4 + 2]);
      float e3 = fast_exp2(dt * A2[q * 4 + 3]);
      h[q * 4 + 0] = fmaf(e0, h[q * 4 + 0], dtx * Bv.x);
      h[q * 4 + 1] = fmaf(e1, h[q * 4 + 1], dtx * Bv.y);
      h[q * 4 + 2] = fmaf(e2, h[q * 4 + 2], dtx * Bv.z);
      h[q * 4 + 3] = fmaf(e3, h[q * 4 + 3], dtx * Bv.w);
    }
  }

  const size_t obase = ((size_t)(b * NC + c) * DIM + d) * NST;
#pragma unroll
  for (int q = 0; q < 4; ++q) {
    float4 sv = {h[q * 4 + 0], h[q * 4 + 1], h[q * 4 + 2], h[q * 4 + 3]};
    *(float4*)&Sout[obase + q * 4] = sv;
  }
  sdtout[(size_t)(b * NC + c) * DIM + d] = sdt;
}

// ---------- Kernel 2: sequential combine; h_init written in-place into S ----------
// 8-deep ring prefetch on both streams keeps ~8 loads in flight per lane.
__global__ __launch_bounds__(256)
void chunk_combine(const float* __restrict__ sdt, float* __restrict__ S,
                   const float* __restrict__ Alog) {
  const int t = blockIdx.x * 256 + threadIdx.x;   // B*D*N = 65536 threads
  const int n = t & (NST - 1);
  const int d = (t >> 4) & (DIM - 1);
  const int b = t >> 15;
  const float a2 = -expf(Alog[(size_t)d * NST + n]) * LOG2E;

  float pfS[8], pfD[8];
#pragma unroll
  for (int c = 0; c < 8; ++c) {
    const size_t idx = ((size_t)(b * NC + c) * DIM + d) * NST + n;
    pfS[c] = S[idx];
    pfD[c] = sdt[(size_t)(b * NC + c) * DIM + d];
  }
  float cur = 0.f;
#pragma unroll
  for (int c = 0; c < NC; ++c) {
    const size_t idx = ((size_t)(b * NC + c) * DIM + d) * NST + n;
    float s = pfS[c & 7];
    float sd = pfD[c & 7];
    S[idx] = cur;                                  // h_init for chunk c
    if (c + 8 < NC) {
      const size_t idx8 = ((size_t)(b * NC + c + 8) * DIM + d) * NST + n;
      pfS[c & 7] = S[idx8];
      pfD[c & 7] = sdt[(size_t)(b * NC + c + 8) * DIM + d];
    }
    cur = fmaf(fast_exp2(sd * a2), cur, s);
  }
}

// ---------- Kernel 3: fused dt + re-scan from h_init, emit y + x*D ----------
__global__ __launch_bounds__(256)
void scan2_fused(const unsigned short* __restrict__ Ad, const unsigned short* __restrict__ Bd,
                 const float* __restrict__ bias, const float* __restrict__ x,
                 const float* __restrict__ Bin, const float* __restrict__ Cin,
                 const float* __restrict__ Alog, const float* __restrict__ Dpar,
                 const float* __restrict__ Hin, float* __restrict__ out) {
  __shared__ float dt_tile[CHUNK][256];           // 32 KiB
  __shared__ float4 Bl[CHUNK * NST / 4];
  __shared__ float4 Cl[CHUNK * NST / 4];
  const int tid = threadIdx.x;
  const int bz = blockIdx.x;
  const int dgrp = bz & 7;
  const int c = (bz >> 3) & (NC - 1);
  const int b = bz >> 9;
  const int d = dgrp * 256 + tid;
  const int l0 = c * CHUNK;

  if (tid < CHUNK * NST / 4)
    Bl[tid] = ((const float4*)(Bin + ((size_t)b * LEN + l0) * NST))[tid];
  else if (tid < CHUNK * NST / 2)
    Cl[tid - CHUNK * NST / 4] = ((const float4*)(Cin + ((size_t)b * LEN + l0) * NST))[tid - CHUNK * NST / 4];

  // 8-deep ring prefetch of x; first 8 issued before MFMA.
  const float* xp = x + ((size_t)b * LEN + l0) * DIM + d;
  float xr[8];
#pragma unroll
  for (int i = 0; i < 8; ++i) xr[i] = xp[(size_t)i * DIM];

  compute_dt_tile(Ad, Bd, bias, b, l0, dgrp, dt_tile);

  // h_init prefetch: overlaps A2 transcendentals + barrier.
  const size_t obase = ((size_t)(b * NC + c) * DIM + d) * NST;
  float h[NST];
#pragma unroll
  for (int q = 0; q < 4; ++q) {
    float4 hv = *(const float4*)&Hin[obase + q * 4];
    h[q * 4 + 0] = hv.x; h[q * 4 + 1] = hv.y; h[q * 4 + 2] = hv.z; h[q * 4 + 3] = hv.w;
  }

  float A2[NST];
  {
    const float4* ap = (const float4*)(Alog + (size_t)d * NST);
#pragma unroll
    for (int q = 0; q < 4; ++q) {
      float4 v = ap[q];
      A2[q * 4 + 0] = -expf(v.x) * LOG2E;
      A2[q * 4 + 1] = -expf(v.y) * LOG2E;
      A2[q * 4 + 2] = -expf(v.z) * LOG2E;
      A2[q * 4 + 3] = -expf(v.w) * LOG2E;
    }
  }
  const float dpar = Dpar[d];
  __syncthreads();

  float* op = out + ((size_t)b * LEN + l0) * DIM + d;

#pragma unroll
  for (int i = 0; i < CHUNK; ++i) {
    float xc = xr[i & 7];
    if (i + 8 < CHUNK) xr[i & 7] = xp[(size_t)(i + 8) * DIM];
    float dt = dt_tile[i][tid];
    float dtx = dt * xc;
    float y0 = 0.f, y1 = 0.f, y2 = 0.f, y3 = 0.f;
#pragma unroll
    for (int q = 0; q < 4; ++q) {
      float4 Bv = Bl[i * 4 + q];
      float4 Cv = Cl[i * 4 + q];
      float e0 = fast_exp2(dt * A2[q * 4 + 0]);
      float e1 = fast_exp2(dt * A2[q * 4 + 1]);
      float e2 = fast_exp2(dt * A2[q * 4 + 2]);
      float e3 = fast_exp2(dt * A2[q * 4 + 3]);
      float hh0 = fmaf(e0, h[q * 4 + 0], dtx * Bv.x);
      float hh1 = fmaf(e1, h[q * 4 + 1], dtx * Bv.y);
      float hh2 = fmaf(e2, h[q * 4 + 2], dtx * Bv.z);
      float hh3 = fmaf(e3, h[q * 4 + 3], dtx * Bv.w);
      h[q * 4 + 0] = hh0; h[q * 4 + 1] = hh1; h[q * 4 + 2] = hh2; h[q * 4 + 3] = hh3;
      float yq = hh0 * Cv.x;
      yq = fmaf(hh1, Cv.y, yq);
      yq = fmaf(hh2, Cv.z, yq);
      yq = fmaf(hh3, Cv.w, yq);
      if (q == 0) y0 = yq; else if (q == 1) y1 = yq; else if (q == 2) y2 = yq; else y3 = yq;
    }
    op[(size_t)i * DIM] = fmaf(xc, dpar, (y0 + y1) + (y2 + y3));
  }
}

}  // namespace

extern "C" void kernel_launch(void* const* d_in, const int* in_sizes, int n_in,
                              void* d_out, int out_size, void* d_ws, size_t ws_size,
                              hipStream_t stream) {
  const float* x     = (const float*)d_in[0];
  const float* delta = (const float*)d_in[1];
  const float* Bin   = (const float*)d_in[2];
  const float* Cin   = (const float*)d_in[3];
  const float* Wdt   = (const float*)d_in[4];
  const float* bdt   = (const float*)d_in[5];
  const float* Alog  = (const float*)d_in[6];
  const float* Dpar  = (const float*)d_in[7];
  float* out = (float*)d_out;

  char* ws = (char*)d_ws;
  size_t off = 0;
  float* S   = (float*)(ws + off); off += (size_t)BSZ * NC * DIM * NST * 4;     // 16 MiB
  float* sdt = (float*)(ws + off); off += (size_t)BSZ * NC * DIM * 4;           // 1 MiB
  unsigned short* Ad = (unsigned short*)(ws + off); off += (size_t)BSZ * LEN * KS * 2;  // 3 MiB
  unsigned short* Bd = (unsigned short*)(ws + off); off += (size_t)DIM * KS * 2;        // 1.5 MiB

  split_bf16<<<(BSZ * LEN * RNK + DIM * RNK) / 256, 256, 0, stream>>>(delta, Wdt, Ad, Bd);
  scan1_fused<<<BSZ * NC * (DIM / 256), 256, 0, stream>>>(Ad, Bd, bdt, x, Bin, Alog, S, sdt);
  chunk_combine<<<BSZ * DIM * NST / 256, 256, 0, stream>>>(sdt, S, Alog);
  scan2_fused<<<BSZ * NC * (DIM / 256), 256, 0, stream>>>(Ad, Bd, bdt, x, Bin, Cin, Alog, Dpar, S, out);
}

// Round 8
// 200.051 us; speedup vs baseline: 1.0829x; 1.0571x over previous
//
#include <hip/hip_runtime.h>
#include <hip/hip_bf16.h>
#include <math.h>

namespace {

constexpr int BSZ = 2, LEN = 2048, DIM = 2048, NST = 16, RNK = 128;
constexpr int NC = 64, CHUNK = LEN / NC;          // 64 chunks of 32
constexpr int KS = 3 * RNK;                       // split-K = 384
constexpr float LOG2E = 1.4426950408889634f;
constexpr float LN2 = 0.6931471805599453f;

using bf16x8 = __attribute__((ext_vector_type(8))) short;
using f32x4  = __attribute__((ext_vector_type(4))) float;

__device__ __forceinline__ float fast_exp2(float x) {
#if __has_builtin(__builtin_amdgcn_exp2f)
  return __builtin_amdgcn_exp2f(x);
#else
  return exp2f(x);
#endif
}

__device__ __forceinline__ unsigned short bf16_rne(float x) {
  __hip_bfloat16 h = __float2bfloat16(x);
  return *(unsigned short*)&h;
}
__device__ __forceinline__ float bf16_tof(unsigned short u) {
  __hip_bfloat16 h = *(__hip_bfloat16*)&u;
  return __bfloat162float(h);
}

// ---------- Kernel 0: split f32 -> bf16 hi/lo, padded K=384 layouts ----------
// Ad: [B*L=4096][384] = [hi | lo | hi];  Bd: [D=2048][384] = [hi | hi | lo]
__global__ __launch_bounds__(256)
void split_bf16(const float* __restrict__ delta, const float* __restrict__ W,
                unsigned short* __restrict__ Ad, unsigned short* __restrict__ Bd) {
  int t = blockIdx.x * 256 + threadIdx.x;
  const int NA = BSZ * LEN * RNK;                 // 524288
  if (t < NA) {
    int row = t >> 7, k = t & (RNK - 1);
    float x = delta[t];
    unsigned short hi = bf16_rne(x);
    unsigned short lo = bf16_rne(x - bf16_tof(hi));
    unsigned short* p = Ad + (size_t)row * KS;
    p[k] = hi; p[RNK + k] = lo; p[2 * RNK + k] = hi;
  } else {
    t -= NA;                                      // 262144 W elements
    int row = t >> 7, k = t & (RNK - 1);
    float x = W[t];
    unsigned short hi = bf16_rne(x);
    unsigned short lo = bf16_rne(x - bf16_tof(hi));
    unsigned short* p = Bd + (size_t)row * KS;
    p[k] = hi; p[RNK + k] = hi; p[2 * RNK + k] = lo;
  }
}

// ---------- Kernel 1: dt = softplus(A' @ B'^T + bias) via bf16 MFMA ----------
// Proven in R1/R3. block = 256 thr (4 waves, 2x2), tile 128x128.
__global__ __launch_bounds__(256)
void dt_mfma(const unsigned short* __restrict__ Ad, const unsigned short* __restrict__ Bd,
             const float* __restrict__ bias, float* __restrict__ dtout) {
  const int lane = threadIdx.x & 63, wid = threadIdx.x >> 6;
  const int wm = wid >> 1, wn = wid & 1;
  const int bm = blockIdx.x & 31, bn = blockIdx.x >> 5;   // M/128=32, N/128=16
  const int r = lane & 15, kg = lane >> 4;

  const unsigned short* arow = Ad + (size_t)(bm * 128 + wm * 64 + r) * KS + kg * 8;
  const unsigned short* brow = Bd + (size_t)(bn * 128 + wn * 64 + r) * KS + kg * 8;

  f32x4 acc[4][4] = {};
#pragma unroll
  for (int ks = 0; ks < KS / 32; ++ks) {          // 12 k-steps of 32
    bf16x8 af[4], bf[4];
#pragma unroll
    for (int m = 0; m < 4; ++m)
      af[m] = *(const bf16x8*)(arow + (size_t)m * 16 * KS + ks * 32);
#pragma unroll
    for (int n = 0; n < 4; ++n)
      bf[n] = *(const bf16x8*)(brow + (size_t)n * 16 * KS + ks * 32);
#pragma unroll
    for (int m = 0; m < 4; ++m)
#pragma unroll
      for (int n = 0; n < 4; ++n)
        acc[m][n] = __builtin_amdgcn_mfma_f32_16x16x32_bf16(af[m], bf[n], acc[m][n], 0, 0, 0);
  }

#pragma unroll
  for (int n = 0; n < 4; ++n) {
    const int col = bn * 128 + wn * 64 + n * 16 + r;
    const float bs = bias[col];
#pragma unroll
    for (int m = 0; m < 4; ++m) {
      const int row0 = bm * 128 + wm * 64 + m * 16 + kg * 4;
#pragma unroll
      for (int j = 0; j < 4; ++j) {
        float z = acc[m][n][j] + bs;
        float sp = fmaxf(z, 0.f) + LN2 * __log2f(1.0f + fast_exp2(-fabsf(z) * LOG2E));
        dtout[(size_t)(row0 + j) * DIM + col] = sp;
      }
    }
  }
}

// ---------- Kernel 2: n-split local scan -> S, sdt ----------
// thread = (d, n-pair): nt = tid&7 handles n = {2nt, 2nt+1}; dl = tid>>3.
// block covers 32 d x 8 nt; grid = B * NC * (D/32) = 8192 blocks.
__global__ __launch_bounds__(256)
void scan1_ns(const float* __restrict__ dtw, const float* __restrict__ x,
              const float* __restrict__ Bin, const float* __restrict__ Alog,
              float* __restrict__ Sout, float* __restrict__ sdtout) {
  __shared__ float dt_l[CHUNK][32];
  __shared__ float x_l[CHUNK][32];
  __shared__ float B_l[CHUNK][NST];
  const int tid = threadIdx.x;
  const int bz = blockIdx.x;
  const int dgrp = bz & 63;                       // D/32 = 64
  const int c = (bz >> 6) & (NC - 1);
  const int b = bz >> 12;
  const int l0 = c * CHUNK;
  const int nt = tid & 7, dl = tid >> 3;
  const int d = dgrp * 32 + dl;
  const int n0 = nt * 2;

  const float* dtp = dtw + ((size_t)b * LEN + l0) * DIM + dgrp * 32;
  const float* xp  = x   + ((size_t)b * LEN + l0) * DIM + dgrp * 32;
#pragma unroll
  for (int j = 0; j < 4; ++j) {
    int idx = tid + j * 256, row = idx >> 5, col = idx & 31;
    dt_l[row][col] = dtp[(size_t)row * DIM + col];
    x_l[row][col]  = xp[(size_t)row * DIM + col];
  }
#pragma unroll
  for (int j = 0; j < 2; ++j) {
    int idx = tid + j * 256, row = idx >> 4, nn = idx & 15;
    B_l[row][nn] = Bin[((size_t)b * LEN + l0 + row) * NST + nn];
  }
  float2 al = *(const float2*)&Alog[(size_t)d * NST + n0];
  const float a20 = -expf(al.x) * LOG2E;
  const float a21 = -expf(al.y) * LOG2E;
  __syncthreads();

  float h0 = 0.f, h1 = 0.f, sdt = 0.f;
#pragma unroll
  for (int i = 0; i < CHUNK; ++i) {
    float dt = dt_l[i][dl];
    float dtx = dt * x_l[i][dl];
    sdt += dt;
    float e0 = fast_exp2(dt * a20);
    float e1 = fast_exp2(dt * a21);
    h0 = fmaf(e0, h0, dtx * B_l[i][n0]);
    h1 = fmaf(e1, h1, dtx * B_l[i][n0 + 1]);
  }
  const size_t ob = ((size_t)(b * NC + c) * DIM + d) * NST + n0;
  float2 hv; hv.x = h0; hv.y = h1;
  *(float2*)&Sout[ob] = hv;
  if (nt == 0) sdtout[(size_t)(b * NC + c) * DIM + d] = sdt;
}

// ---------- Kernel 3: sequential combine; h_init written in-place into S ----------
__global__ __launch_bounds__(256)
void chunk_combine(const float* __restrict__ sdt, float* __restrict__ S,
                   const float* __restrict__ Alog) {
  const int t = blockIdx.x * 256 + threadIdx.x;   // B*D*N = 65536 threads
  const int n = t & (NST - 1);
  const int d = (t >> 4) & (DIM - 1);
  const int b = t >> 15;
  const float a2 = -expf(Alog[(size_t)d * NST + n]) * LOG2E;

  float pfS[8], pfD[8];
#pragma unroll
  for (int c = 0; c < 8; ++c) {
    const size_t idx = ((size_t)(b * NC + c) * DIM + d) * NST + n;
    pfS[c] = S[idx];
    pfD[c] = sdt[(size_t)(b * NC + c) * DIM + d];
  }
  float cur = 0.f;
#pragma unroll
  for (int c = 0; c < NC; ++c) {
    const size_t idx = ((size_t)(b * NC + c) * DIM + d) * NST + n;
    float s = pfS[c & 7];
    float sd = pfD[c & 7];
    S[idx] = cur;                                  // h_init for chunk c
    if (c + 8 < NC) {
      const size_t idx8 = ((size_t)(b * NC + c + 8) * DIM + d) * NST + n;
      pfS[c & 7] = S[idx8];
      pfD[c & 7] = sdt[(size_t)(b * NC + c + 8) * DIM + d];
    }
    cur = fmaf(fast_exp2(sd * a2), cur, s);
  }
}

// ---------- Kernel 4: n-split re-scan from h_init, emit y + x*D ----------
__global__ __launch_bounds__(256)
void scan2_ns(const float* __restrict__ dtw, const float* __restrict__ x,
              const float* __restrict__ Bin, const float* __restrict__ Cin,
              const float* __restrict__ Alog, const float* __restrict__ Dpar,
              const float* __restrict__ Hin, float* __restrict__ out) {
  __shared__ float dt_l[CHUNK][32];
  __shared__ float x_l[CHUNK][32];
  __shared__ float B_l[CHUNK][NST];
  __shared__ float C_l[CHUNK][NST];
  const int tid = threadIdx.x;
  const int bz = blockIdx.x;
  const int dgrp = bz & 63;
  const int c = (bz >> 6) & (NC - 1);
  const int b = bz >> 12;
  const int l0 = c * CHUNK;
  const int nt = tid & 7, dl = tid >> 3;
  const int d = dgrp * 32 + dl;
  const int n0 = nt * 2;

  const float* dtp = dtw + ((size_t)b * LEN + l0) * DIM + dgrp * 32;
  const float* xp  = x   + ((size_t)b * LEN + l0) * DIM + dgrp * 32;
#pragma unroll
  for (int j = 0; j < 4; ++j) {
    int idx = tid + j * 256, row = idx >> 5, col = idx & 31;
    dt_l[row][col] = dtp[(size_t)row * DIM + col];
    x_l[row][col]  = xp[(size_t)row * DIM + col];
  }
#pragma unroll
  for (int j = 0; j < 2; ++j) {
    int idx = tid + j * 256, row = idx >> 4, nn = idx & 15;
    B_l[row][nn] = Bin[((size_t)b * LEN + l0 + row) * NST + nn];
    C_l[row][nn] = Cin[((size_t)b * LEN + l0 + row) * NST + nn];
  }
  float2 al = *(const float2*)&Alog[(size_t)d * NST + n0];
  const float a20 = -expf(al.x) * LOG2E;
  const float a21 = -expf(al.y) * LOG2E;
  const float dpar = Dpar[d];

  const size_t ob = ((size_t)(b * NC + c) * DIM + d) * NST + n0;
  float2 hv = *(const float2*)&Hin[ob];
  float h0 = hv.x, h1 = hv.y;
  __syncthreads();

  float* op = out + ((size_t)b * LEN + l0) * DIM + d;

#pragma unroll
  for (int i = 0; i < CHUNK; ++i) {
    float dt = dt_l[i][dl];
    float xv = x_l[i][dl];
    float dtx = dt * xv;
    float e0 = fast_exp2(dt * a20);
    float e1 = fast_exp2(dt * a21);
    h0 = fmaf(e0, h0, dtx * B_l[i][n0]);
    h1 = fmaf(e1, h1, dtx * B_l[i][n0 + 1]);
    float yp = h0 * C_l[i][n0];
    yp = fmaf(h1, C_l[i][n0 + 1], yp);
    // sum over the 8 nt lanes (consecutive lanes within each dl group)
    yp += __shfl_xor(yp, 1, 8);
    yp += __shfl_xor(yp, 2, 8);
    yp += __shfl_xor(yp, 4, 8);
    if (nt == 0) op[(size_t)i * DIM] = fmaf(xv, dpar, yp);
  }
}

}  // namespace

extern "C" void kernel_launch(void* const* d_in, const int* in_sizes, int n_in,
                              void* d_out, int out_size, void* d_ws, size_t ws_size,
                              hipStream_t stream) {
  const float* x     = (const float*)d_in[0];
  const float* delta = (const float*)d_in[1];
  const float* Bin   = (const float*)d_in[2];
  const float* Cin   = (const float*)d_in[3];
  const float* Wdt   = (const float*)d_in[4];
  const float* bdt   = (const float*)d_in[5];
  const float* Alog  = (const float*)d_in[6];
  const float* Dpar  = (const float*)d_in[7];
  float* out = (float*)d_out;

  char* ws = (char*)d_ws;
  size_t off = 0;
  float* dtw = (float*)(ws + off); off += (size_t)BSZ * LEN * DIM * 4;          // 32 MiB
  float* S   = (float*)(ws + off); off += (size_t)BSZ * NC * DIM * NST * 4;     // 16 MiB
  float* sdt = (float*)(ws + off); off += (size_t)BSZ * NC * DIM * 4;           // 1 MiB
  unsigned short* Ad = (unsigned short*)(ws + off); off += (size_t)BSZ * LEN * KS * 2;  // 3 MiB
  unsigned short* Bd = (unsigned short*)(ws + off); off += (size_t)DIM * KS * 2;        // 1.5 MiB

  split_bf16<<<(BSZ * LEN * RNK + DIM * RNK) / 256, 256, 0, stream>>>(delta, Wdt, Ad, Bd);
  dt_mfma<<<(BSZ * LEN / 128) * (DIM / 128), 256, 0, stream>>>(Ad, Bd, bdt, dtw);
  scan1_ns<<<BSZ * NC * (DIM / 32), 256, 0, stream>>>(dtw, x, Bin, Alog, S, sdt);
  chunk_combine<<<BSZ * DIM * NST / 256, 256, 0, stream>>>(sdt, S, Alog);
  scan2_ns<<<BSZ * NC * (DIM / 32), 256, 0, stream>>>(dtw, x, Bin, Cin, Alog, Dpar, S, out);
}